// Round 4
// baseline (638.214 us; speedup 1.0000x reference)
//
#include <hip/hip_runtime.h>
#include <hip/hip_bf16.h>

#define H 1024
#define S 1024
#define B 32
#define K2 2048  // 2*H

typedef unsigned short u16;
typedef __attribute__((ext_vector_type(8))) short short8;     // 8 bf16 (4 VGPRs) — MFMA A/B frag
typedef __attribute__((ext_vector_type(8))) unsigned short u16x8;
typedef __attribute__((ext_vector_type(4))) float floatx4;    // MFMA C/D frag

__device__ __forceinline__ u16 f2bf(float f) {
  unsigned u = __float_as_uint(f);
  u += 0x7FFFu + ((u >> 16) & 1u);   // RNE to bf16
  return (u16)(u >> 16);
}

// async global->LDS, 16B per lane; global addr is PER-LANE, LDS dest = wave-uniform base + lane*16
__device__ __forceinline__ void gld_lds16(const void* g, void* l) {
  __builtin_amdgcn_global_load_lds(
      (const __attribute__((address_space(1))) unsigned int*)g,
      (__attribute__((address_space(3))) unsigned int*)l, 16, 0, 0);
}

// fast tanh: 1 - 2/(e^{2x}+1). Exact +-1 asymptotes (t=inf -> 1, t=0 -> -1),
// ~6 VALU ops vs ~25 for libm tanhf. |err| ~ 1e-7.
__device__ __forceinline__ float tanh_fast(float x) {
  float t = __expf(2.0f * x);
  return 1.0f - 2.0f / (t + 1.0f);
}

// W_attn (H,3H) fp32 -> W_e bf16 (H,2H)
__global__ void conv_we_k(const float* __restrict__ W, u16* __restrict__ dst) {
  const int h = blockIdx.x;
  const int t = threadIdx.x * 8;
  const float* sp = W + (size_t)h * 3072 + H + t;
  u16* dp = dst + (size_t)h * K2 + t;
  floatx4 x = *(const floatx4*)sp;
  floatx4 y = *(const floatx4*)(sp + 4);
  u16x8 o;
  o[0] = f2bf(x[0]); o[1] = f2bf(x[1]); o[2] = f2bf(x[2]); o[3] = f2bf(x[3]);
  o[4] = f2bf(y[0]); o[5] = f2bf(y[1]); o[6] = f2bf(y[2]); o[7] = f2bf(y[3]);
  *(u16x8*)dp = o;
}

// enc (S,B,2H) fp32 -> encb (B,S,2H) bf16. One block per (s,b) row: read 8KB
// contiguous, write 4KB contiguous. Pure BW pass (~384MB total traffic).
__global__ void conv_enc_k(const float* __restrict__ enc, u16* __restrict__ dst) {
  const int sb = blockIdx.x;          // s*B + b
  const int s = sb >> 5;
  const int b = sb & 31;
  const int t = threadIdx.x * 8;
  const float* sp = enc + (size_t)sb * K2 + t;
  u16* dp = dst + ((size_t)b * S + s) * K2 + t;
  floatx4 x = *(const floatx4*)sp;
  floatx4 y = *(const floatx4*)(sp + 4);
  u16x8 o;
  o[0] = f2bf(x[0]); o[1] = f2bf(x[1]); o[2] = f2bf(x[2]); o[3] = f2bf(x[3]);
  o[4] = f2bf(y[0]); o[5] = f2bf(y[1]); o[6] = f2bf(y[2]); o[7] = f2bf(y[3]);
  *(u16x8*)dp = o;
}

// h_proj[b,h] = hidden[b,:] . W_attn[h, 0:H] + b_attn[h]   (fp32 exact path)
__global__ void hproj_k(const float* __restrict__ hidden, const float* __restrict__ W,
                        const float* __restrict__ b_attn, float* __restrict__ hp) {
  const int lane = threadIdx.x & 63;
  const int h = (blockIdx.x * blockDim.x + threadIdx.x) >> 6;
  float wr[16];
#pragma unroll
  for (int i = 0; i < 16; i++) wr[i] = W[(size_t)h * 3072 + lane + i * 64];
  for (int b = 0; b < B; b++) {
    float d = 0.f;
#pragma unroll
    for (int i = 0; i < 16; i++) d = fmaf(wr[i], hidden[b * H + lane + i * 64], d);
#pragma unroll
    for (int off = 32; off; off >>= 1) d += __shfl_xor(d, off);
    if (lane == 0) hp[b * H + h] = d + b_attn[h];
  }
}

#define BM 128
#define BN 128
#define BK 64

// bf16 GEMM, R1-proven 2-barrier structure, BK=64:
//  - single-buffered 32KB LDS; per iter: stage (4+4 gld_lds16), sync, 16 ds_read_b128
//    + 32 MFMA, sync. 32 iterations (half the barrier count of BK=32).
//  - LDS row = 64 bf16 (128B) = 8 segs of 8; logical seg s of row r stored at
//    physical s ^ (r&7) (pre-swizzled GLOBAL source, linear LDS dest — rule 21).
//    Reader: physical = (kh*4+kgrp) ^ (R&7). Quarter-wave bank check: 2-way max (free).
//  - bid mapping: id%8 = mtile (R1's; measured FETCH 260MB vs 531MB for id%8=ntile —
//    cross-XCD simultaneous same-line misses don't coalesce, keep same-Bw-slice
//    blocks time-adjacent instead).
__global__ __launch_bounds__(256) void gemm_bf16_k(
    const u16* __restrict__ A,      // (B,S,2H) bf16
    const u16* __restrict__ Bw,     // (H,2H) bf16
    const float* __restrict__ hp, const float* __restrict__ vw,
    float* __restrict__ attn) {
  __shared__ __align__(16) u16 sA[BM * BK];   // 16 KB
  __shared__ __align__(16) u16 sB[BN * BK];   // 16 KB
  const int tid = threadIdx.x;
  const int bid = blockIdx.x;
  const int ntile = bid >> 8;
  const int b = (bid & 255) >> 3;
  const int mtile = bid & 7;
  const int s0 = mtile * BM;
  const int h0 = ntile * BN;

  const int lane = tid & 63;
  const int wv = tid >> 6;
  const int wm = (wv >> 1) * 64;
  const int wn = (wv & 1) * 64;
  const int fr = lane & 15;         // frag row
  const int kgrp = lane >> 4;       // k sub-chunk 0..3 within one MFMA K=32

  const int lr8 = lane >> 3;        // staging: row-within-8 (0..7)
  const int sg8 = lane & 7;         // staging: physical seg 0..7
  const int ssw = (sg8 ^ lr8) << 3; // pre-swizzled global k-offset (elems)

  const u16* Abase = A + (size_t)b * S * K2;

  floatx4 acc[4][4];
#pragma unroll
  for (int i = 0; i < 4; i++)
#pragma unroll
    for (int j = 0; j < 4; j++) acc[i][j] = (floatx4){0.f, 0.f, 0.f, 0.f};

  for (int k0 = 0; k0 < K2; k0 += BK) {
    __syncthreads();   // prev frag reads done before overwrite
    // stage: 4 calls x (8 waves-rows) cover 128 rows x 128B per operand
#pragma unroll
    for (int p = 0; p < 4; p++) {
      const int r = p * 32 + wv * 8 + lr8;   // tile row; r&7 == lr8
      gld_lds16(Abase + (size_t)(s0 + r) * K2 + k0 + ssw,
                (char*)sA + (p * 32 + wv * 8) * 128);
      gld_lds16(Bw + (size_t)(h0 + r) * K2 + k0 + ssw,
                (char*)sB + (p * 32 + wv * 8) * 128);
    }
    __syncthreads();   // drains vmcnt(0): staged data visible

#pragma unroll
    for (int kh = 0; kh < 2; ++kh) {   // two K=32 MFMA windows per BK=64
      const int ks = kh * 4 + kgrp;    // logical seg 0..7
      short8 af[4], bfr[4];
#pragma unroll
      for (int mf = 0; mf < 4; mf++) {
        const int R = wm + mf * 16 + fr;
        af[mf] = *(const short8*)&sA[R * BK + ((ks ^ (R & 7)) << 3)];
      }
#pragma unroll
      for (int nf = 0; nf < 4; nf++) {
        const int R = wn + nf * 16 + fr;
        bfr[nf] = *(const short8*)&sB[R * BK + ((ks ^ (R & 7)) << 3)];
      }
#pragma unroll
      for (int mf = 0; mf < 4; mf++)
#pragma unroll
        for (int nf = 0; nf < 4; nf++)
          acc[mf][nf] =
              __builtin_amdgcn_mfma_f32_16x16x32_bf16(af[mf], bfr[nf], acc[mf][nf], 0, 0, 0);
    }
  }

  // Epilogue. C/D map: col = lane&15, row = (lane>>4)*4 + reg
  const int col = fr;
  const int rgrp = lane >> 4;
  float hv[4], vv[4];
#pragma unroll
  for (int nf = 0; nf < 4; nf++) {
    const int h = h0 + wn + nf * 16 + col;
    hv[nf] = hp[b * H + h];
    vv[nf] = vw[h];
  }
#pragma unroll
  for (int mf = 0; mf < 4; mf++) {
#pragma unroll
    for (int r = 0; r < 4; r++) {
      float part = 0.f;
#pragma unroll
      for (int nf = 0; nf < 4; nf++) part += tanh_fast(acc[mf][nf][r] + hv[nf]) * vv[nf];
      part += __shfl_xor(part, 1);
      part += __shfl_xor(part, 2);
      part += __shfl_xor(part, 4);
      part += __shfl_xor(part, 8);   // sum over the 16 col-lanes; preserves rgrp
      if (col == 0)
        atomicAdd(&attn[b * S + s0 + wm + mf * 16 + rgrp * 4 + r], part);
    }
  }
}

__global__ void softmax_k(const float* __restrict__ attn, float* __restrict__ out) {
  __shared__ float red[8];
  const int b = blockIdx.x;
  const int tid = threadIdx.x;
  const float* row = attn + b * S;
  float v[4];
#pragma unroll
  for (int i = 0; i < 4; i++) v[i] = row[tid + i * 256];
  float m = fmaxf(fmaxf(v[0], v[1]), fmaxf(v[2], v[3]));
#pragma unroll
  for (int off = 32; off; off >>= 1) m = fmaxf(m, __shfl_xor(m, off));
  if ((tid & 63) == 0) red[tid >> 6] = m;
  __syncthreads();
  m = fmaxf(fmaxf(red[0], red[1]), fmaxf(red[2], red[3]));
  float e[4], sum = 0.f;
#pragma unroll
  for (int i = 0; i < 4; i++) { e[i] = __expf(v[i] - m); sum += e[i]; }
#pragma unroll
  for (int off = 32; off; off >>= 1) sum += __shfl_xor(sum, off);
  __syncthreads();
  if ((tid & 63) == 0) red[4 + (tid >> 6)] = sum;
  __syncthreads();
  sum = red[4] + red[5] + red[6] + red[7];
  const float inv = 1.0f / sum;
#pragma unroll
  for (int i = 0; i < 4; i++) out[b * S + tid + i * 256] = e[i] * inv;
}

extern "C" void kernel_launch(void* const* d_in, const int* in_sizes, int n_in,
                              void* d_out, int out_size, void* d_ws, size_t ws_size,
                              hipStream_t stream) {
  const float* enc    = (const float*)d_in[0];  // (S,B,2H)
  const float* hidden = (const float*)d_in[1];  // (B,H)
  // d_in[2] = cell — unused by the reference
  const float* W_attn = (const float*)d_in[3];  // (H,3H)
  const float* b_attn = (const float*)d_in[4];  // (H)
  const float* v_w    = (const float*)d_in[5];  // (H)
  float* out = (float*)d_out;                   // (B,S)

  char* ws = (char*)d_ws;
  float* attn = (float*)ws;                                  // 128 KiB
  float* hp   = (float*)(ws + 131072);                       // 128 KiB
  u16* Web    = (u16*)(ws + 262144);                         // 4 MiB
  u16* encb   = (u16*)(ws + 4456448);                        // 128 MiB (B,S,2H) bf16

  hipMemsetAsync(attn, 0, B * S * sizeof(float), stream);    // ws is 0xAA-poisoned each call
  conv_we_k<<<H, 256, 0, stream>>>(W_attn, Web);
  hproj_k<<<256, 256, 0, stream>>>(hidden, W_attn, b_attn, hp);
  conv_enc_k<<<S * B, 256, 0, stream>>>(enc, encb);
  gemm_bf16_k<<<2048, 256, 0, stream>>>(encb, Web, hp, v_w, attn);
  softmax_k<<<B, 256, 0, stream>>>(attn, out);
}

// Round 5
// 573.780 us; speedup vs baseline: 1.1123x; 1.1123x over previous
//
#include <hip/hip_runtime.h>
#include <hip/hip_bf16.h>

#define H 1024
#define S 1024
#define B 32
#define K2 2048  // 2*H

typedef unsigned short u16;
typedef __attribute__((ext_vector_type(8))) short short8;     // 8 bf16 (4 VGPRs) — MFMA A/B frag
typedef __attribute__((ext_vector_type(8))) unsigned short u16x8;
typedef __attribute__((ext_vector_type(4))) float floatx4;    // MFMA C/D frag

__device__ __forceinline__ u16 f2bf(float f) {
  unsigned u = __float_as_uint(f);
  u += 0x7FFFu + ((u >> 16) & 1u);   // RNE to bf16
  return (u16)(u >> 16);
}

// async global->LDS, 16B per lane; global addr is PER-LANE, LDS dest = wave-uniform base + lane*16
__device__ __forceinline__ void gld_lds16(const void* g, void* l) {
  __builtin_amdgcn_global_load_lds(
      (const __attribute__((address_space(1))) unsigned int*)g,
      (__attribute__((address_space(3))) unsigned int*)l, 16, 0, 0);
}

// fast tanh: 1 - 2/(e^{2x}+1). Exact +-1 asymptotes, ~6 VALU ops, |err| ~ 1e-7.
__device__ __forceinline__ float tanh_fast(float x) {
  float t = __expf(2.0f * x);
  return 1.0f - 2.0f / (t + 1.0f);
}

// W_attn (H,3H) fp32 -> W_e bf16 (H,2H)
__global__ void conv_we_k(const float* __restrict__ W, u16* __restrict__ dst) {
  const int h = blockIdx.x;
  const int t = threadIdx.x * 8;
  const float* sp = W + (size_t)h * 3072 + H + t;
  u16* dp = dst + (size_t)h * K2 + t;
  floatx4 x = *(const floatx4*)sp;
  floatx4 y = *(const floatx4*)(sp + 4);
  u16x8 o;
  o[0] = f2bf(x[0]); o[1] = f2bf(x[1]); o[2] = f2bf(x[2]); o[3] = f2bf(x[3]);
  o[4] = f2bf(y[0]); o[5] = f2bf(y[1]); o[6] = f2bf(y[2]); o[7] = f2bf(y[3]);
  *(u16x8*)dp = o;
}

// enc (S,B,2H) fp32 -> encb (B,S,2H) bf16. Pure BW pass (~384MB traffic).
__global__ void conv_enc_k(const float* __restrict__ enc, u16* __restrict__ dst) {
  const int sb = blockIdx.x;          // s*B + b
  const int s = sb >> 5;
  const int b = sb & 31;
  const int t = threadIdx.x * 8;
  const float* sp = enc + (size_t)sb * K2 + t;
  u16* dp = dst + ((size_t)b * S + s) * K2 + t;
  floatx4 x = *(const floatx4*)sp;
  floatx4 y = *(const floatx4*)(sp + 4);
  u16x8 o;
  o[0] = f2bf(x[0]); o[1] = f2bf(x[1]); o[2] = f2bf(x[2]); o[3] = f2bf(x[3]);
  o[4] = f2bf(y[0]); o[5] = f2bf(y[1]); o[6] = f2bf(y[2]); o[7] = f2bf(y[3]);
  *(u16x8*)dp = o;
}

// h_proj[b,h] = hidden[b,:] . W_attn[h, 0:H] + b_attn[h]   (fp32 exact path)
__global__ void hproj_k(const float* __restrict__ hidden, const float* __restrict__ W,
                        const float* __restrict__ b_attn, float* __restrict__ hp) {
  const int lane = threadIdx.x & 63;
  const int h = (blockIdx.x * blockDim.x + threadIdx.x) >> 6;
  float wr[16];
#pragma unroll
  for (int i = 0; i < 16; i++) wr[i] = W[(size_t)h * 3072 + lane + i * 64];
  for (int b = 0; b < B; b++) {
    float d = 0.f;
#pragma unroll
    for (int i = 0; i < 16; i++) d = fmaf(wr[i], hidden[b * H + lane + i * 64], d);
#pragma unroll
    for (int off = 32; off; off >>= 1) d += __shfl_xor(d, off);
    if (lane == 0) hp[b * H + h] = d + b_attn[h];
  }
}

// ===================== 256x256 8-phase GEMM (T2+T3+T4+T5) =====================
// 8 waves (2M x 4N), per-wave output 128x64, BK=64, 32 K-tiles, 2 tiles/iter.
// LDS 128KB: sA/sB x 2 bufs x 2 regions x (128 rows x 64 bf16). Region = the
// consumption unit: A grouped by mh (rows wr*128+mh*64+0..63), B by nh
// (rows wc*64+nh*32+0..31). Stage = 2 gld_lds16 per region (16KB).
// Row seg-swizzle phys = logical ^ (row&7), applied on the GLOBAL source
// (linear LDS dest, rule 21); reader applies same XOR. 0-conflict (R1/R4).
// Per phase: 12 ds_read_b128 || 1 half-tile stage -> s_barrier ->
// lgkmcnt(0)+sched_barrier -> setprio(1) 16 MFMA setprio(0) -> [vmcnt(4) at
// P4/P8 only] -> s_barrier. Staged halves always target regions whose last
// reader finished at the previous barrier (rotation verified per-phase).
#define BM 256
#define BN 256
#define BK 64
#define NKT 32   // K2/BK

#define STG_A(BUF, MH, KT)                                                    \
  { _Pragma("unroll") for (int c_ = 0; c_ < 2; ++c_) {                        \
      const int ri_ = c_ * 64 + srow;                                         \
      const int rg_ = ((ri_ >> 6) << 7) + (MH) * 64 + (ri_ & 63);             \
      const int lg_ = sseg ^ (ri_ & 7);                                       \
      gld_lds16(Ab + (size_t)(s0 + rg_) * K2 + (KT) * BK + (lg_ << 3),        \
                (char*)&sA[BUF][MH][0] + c_ * 8192 + wv * 1024); } }

#define STG_B(BUF, NH, KT)                                                    \
  { _Pragma("unroll") for (int c_ = 0; c_ < 2; ++c_) {                        \
      const int ri_ = c_ * 64 + srow;                                         \
      const int rg_ = ((ri_ >> 5) << 6) + (NH) * 32 + (ri_ & 31);             \
      const int lg_ = sseg ^ (ri_ & 7);                                       \
      gld_lds16(Bw + (size_t)(h0 + rg_) * K2 + (KT) * BK + (lg_ << 3),        \
                (char*)&sB[BUF][NH][0] + c_ * 8192 + wv * 1024); } }

#define PHASE(BUF, MH, NH, STAGE, DRAIN)                                      \
  {                                                                           \
    short8 af_[4][2], bf_[2][2];                                              \
    _Pragma("unroll") for (int m_ = 0; m_ < 4; ++m_)                          \
      _Pragma("unroll") for (int k_ = 0; k_ < 2; ++k_)                        \
        af_[m_][k_] = *(const short8*)(&sA[BUF][MH][0] + aoff[m_][k_]);       \
    _Pragma("unroll") for (int n_ = 0; n_ < 2; ++n_)                          \
      _Pragma("unroll") for (int k_ = 0; k_ < 2; ++k_)                        \
        bf_[n_][k_] = *(const short8*)(&sB[BUF][NH][0] + boff[n_][k_]);       \
    STAGE                                                                     \
    __builtin_amdgcn_s_barrier();                                             \
    asm volatile("s_waitcnt lgkmcnt(0)" ::: "memory");                        \
    __builtin_amdgcn_sched_barrier(0);                                        \
    __builtin_amdgcn_s_setprio(1);                                            \
    _Pragma("unroll") for (int k_ = 0; k_ < 2; ++k_)                          \
      _Pragma("unroll") for (int m_ = 0; m_ < 4; ++m_)                        \
        _Pragma("unroll") for (int n_ = 0; n_ < 2; ++n_)                      \
          acc[(MH) * 4 + m_][(NH) * 2 + n_] =                                 \
              __builtin_amdgcn_mfma_f32_16x16x32_bf16(                        \
                  af_[m_][k_], bf_[n_][k_],                                   \
                  acc[(MH) * 4 + m_][(NH) * 2 + n_], 0, 0, 0);                \
    __builtin_amdgcn_s_setprio(0);                                            \
    DRAIN                                                                     \
    __builtin_amdgcn_s_barrier();                                             \
  }

__global__ __launch_bounds__(512, 2) void gemm_8ph_k(
    const u16* __restrict__ A,      // (B,S,2H) bf16
    const u16* __restrict__ Bw,     // (H,2H) bf16
    const float* __restrict__ hp, const float* __restrict__ vw,
    float* __restrict__ attn) {
  __shared__ __align__(16) u16 sA[2][2][128 * 64];   // [buf][mh][row*64+k] 64KB
  __shared__ __align__(16) u16 sB[2][2][128 * 64];   // [buf][nh][row*64+k] 64KB

  const int tid = threadIdx.x;
  const int lane = tid & 63;
  const int wv = tid >> 6;       // 0..7
  const int wr = wv >> 2;        // 0..1 (M wave-row)
  const int wc = wv & 3;         // 0..3 (N wave-col)
  const int fr = lane & 15;
  const int kgrp = lane >> 4;    // 0..3
  const int srow = wv * 8 + (lane >> 3);  // staging rowidx within 64-row call
  const int sseg = lane & 7;              // staging physical seg

  const int bid = blockIdx.x;             // 512 blocks: ntile*128 + b*4 + mtile
  const int ntile = bid >> 7;             // 0..3
  const int b = (bid >> 2) & 31;
  const int mtile = bid & 3;              // fastest-varying (R1 lesson)
  const int s0 = mtile * BM;
  const int h0 = ntile * BN;

  const u16* Ab = A + (size_t)b * S * K2;

  // thread-invariant frag byte offsets (u16 units) within a 16KB region
  int aoff[4][2], boff[2][2];
#pragma unroll
  for (int m = 0; m < 4; ++m)
#pragma unroll
    for (int k = 0; k < 2; ++k)
      aoff[m][k] = (wr * 64 + m * 16 + fr) * 64 + ((((k << 2) + kgrp) ^ (fr & 7)) << 3);
#pragma unroll
  for (int n = 0; n < 2; ++n)
#pragma unroll
    for (int k = 0; k < 2; ++k)
      boff[n][k] = (wc * 32 + n * 16 + fr) * 64 + ((((k << 2) + kgrp) ^ (fr & 7)) << 3);

  floatx4 acc[8][4];
#pragma unroll
  for (int i = 0; i < 8; ++i)
#pragma unroll
    for (int j = 0; j < 4; ++j) acc[i][j] = (floatx4){0.f, 0.f, 0.f, 0.f};

  // ---- prologue: tile0 all 4 halves + tile1 {B-nh0, A-mh0} (12 loads) ----
  STG_B(0, 0, 0) STG_A(0, 0, 0) STG_A(0, 1, 0) STG_B(0, 1, 0)
  STG_B(1, 0, 1) STG_A(1, 0, 1)
  asm volatile("s_waitcnt vmcnt(4)" ::: "memory");   // tile0 landed; tile1 pair in flight
  __builtin_amdgcn_s_barrier();

  // ---- main loop: iter computes tiles 2i (buf0, P1-4) and 2i+1 (buf1, P5-8) ----
  for (int it = 0; it < 16; ++it) {
    const int t1 = 2 * it + 1, t2 = 2 * it + 2, t3 = 2 * it + 3;
    const bool Lst = (it == 15);
    // P1 (mh0,nh0): stage A-mh1(t1) -> sA[1][1] (freed at prev P8)
    PHASE(0, 0, 0, STG_A(1, 1, t1), )
    // P2 (mh1,nh0): stage B-nh1(t1) -> sB[1][1] (freed at prev P8)
    PHASE(0, 1, 0, STG_B(1, 1, t1), )
    // P3 (mh0,nh1): stage B-nh0(t2) -> sB[0][0] (freed at P2)
    PHASE(0, 0, 1, if (!Lst) { STG_B(0, 0, t2) }, )
    // P4 (mh1,nh1): stage A-mh0(t2) -> sA[0][0] (freed at P3); K-tile drain
    PHASE(0, 1, 1, if (!Lst) { STG_A(0, 0, t2) },
          if (Lst) { asm volatile("s_waitcnt vmcnt(0)" ::: "memory"); }
          else     { asm volatile("s_waitcnt vmcnt(4)" ::: "memory"); } )
    // P5 (mh0,nh0): stage A-mh1(t2) -> sA[0][1] (freed at P4)
    PHASE(1, 0, 0, if (!Lst) { STG_A(0, 1, t2) }, )
    // P6 (mh1,nh0): stage B-nh1(t2) -> sB[0][1] (freed at P4)
    PHASE(1, 1, 0, if (!Lst) { STG_B(0, 1, t2) }, )
    // P7 (mh0,nh1): stage B-nh0(t3) -> sB[1][0] (freed at P6)
    PHASE(1, 0, 1, if (!Lst) { STG_B(1, 0, t3) }, )
    // P8 (mh1,nh1): stage A-mh0(t3) -> sA[1][0] (freed at P7); K-tile drain
    PHASE(1, 1, 1, if (!Lst) { STG_A(1, 0, t3) },
          if (!Lst) { asm volatile("s_waitcnt vmcnt(4)" ::: "memory"); } )
  }

  // ---- epilogue: tanh + v-weighted h-reduction. C/D: col=lane&15, row=(lane>>4)*4+reg
  const int col = fr;
  const int rgrp = lane >> 4;
  float hv[4], vv[4];
#pragma unroll
  for (int nf = 0; nf < 4; ++nf) {
    const int h = h0 + wc * 64 + nf * 16 + col;
    hv[nf] = hp[b * H + h];
    vv[nf] = vw[h];
  }
#pragma unroll
  for (int mf = 0; mf < 8; ++mf) {
#pragma unroll
    for (int r = 0; r < 4; ++r) {
      float part = 0.f;
#pragma unroll
      for (int nf = 0; nf < 4; ++nf) part += tanh_fast(acc[mf][nf][r] + hv[nf]) * vv[nf];
      part += __shfl_xor(part, 1);
      part += __shfl_xor(part, 2);
      part += __shfl_xor(part, 4);
      part += __shfl_xor(part, 8);   // sum over 16 col-lanes; preserves rgrp
      if (col == 0)
        atomicAdd(&attn[b * S + s0 + wr * 128 + mf * 16 + rgrp * 4 + r], part);
    }
  }
}

__global__ void softmax_k(const float* __restrict__ attn, float* __restrict__ out) {
  __shared__ float red[8];
  const int b = blockIdx.x;
  const int tid = threadIdx.x;
  const float* row = attn + b * S;
  float v[4];
#pragma unroll
  for (int i = 0; i < 4; i++) v[i] = row[tid + i * 256];
  float m = fmaxf(fmaxf(v[0], v[1]), fmaxf(v[2], v[3]));
#pragma unroll
  for (int off = 32; off; off >>= 1) m = fmaxf(m, __shfl_xor(m, off));
  if ((tid & 63) == 0) red[tid >> 6] = m;
  __syncthreads();
  m = fmaxf(fmaxf(red[0], red[1]), fmaxf(red[2], red[3]));
  float e[4], sum = 0.f;
#pragma unroll
  for (int i = 0; i < 4; i++) { e[i] = __expf(v[i] - m); sum += e[i]; }
#pragma unroll
  for (int off = 32; off; off >>= 1) sum += __shfl_xor(sum, off);
  __syncthreads();
  if ((tid & 63) == 0) red[4 + (tid >> 6)] = sum;
  __syncthreads();
  sum = red[4] + red[5] + red[6] + red[7];
  const float inv = 1.0f / sum;
#pragma unroll
  for (int i = 0; i < 4; i++) out[b * S + tid + i * 256] = e[i] * inv;
}

extern "C" void kernel_launch(void* const* d_in, const int* in_sizes, int n_in,
                              void* d_out, int out_size, void* d_ws, size_t ws_size,
                              hipStream_t stream) {
  const float* enc    = (const float*)d_in[0];  // (S,B,2H)
  const float* hidden = (const float*)d_in[1];  // (B,H)
  // d_in[2] = cell — unused by the reference
  const float* W_attn = (const float*)d_in[3];  // (H,3H)
  const float* b_attn = (const float*)d_in[4];  // (H)
  const float* v_w    = (const float*)d_in[5];  // (H)
  float* out = (float*)d_out;                   // (B,S)

  char* ws = (char*)d_ws;
  float* attn = (float*)ws;                                  // 128 KiB
  float* hp   = (float*)(ws + 131072);                       // 128 KiB
  u16* Web    = (u16*)(ws + 262144);                         // 4 MiB
  u16* encb   = (u16*)(ws + 4456448);                        // 128 MiB (B,S,2H) bf16

  hipMemsetAsync(attn, 0, B * S * sizeof(float), stream);    // ws is 0xAA-poisoned each call
  conv_we_k<<<H, 256, 0, stream>>>(W_attn, Web);
  hproj_k<<<256, 256, 0, stream>>>(hidden, W_attn, b_attn, hp);
  conv_enc_k<<<S * B, 256, 0, stream>>>(enc, encb);
  gemm_8ph_k<<<512, 512, 0, stream>>>(encb, Web, hp, v_w, attn);
  softmax_k<<<B, 256, 0, stream>>>(attn, out);
}

// Round 6
// 547.032 us; speedup vs baseline: 1.1667x; 1.0489x over previous
//
#include <hip/hip_runtime.h>
#include <hip/hip_bf16.h>

#define H 1024
#define S 1024
#define B 32
#define K2 2048  // 2*H

typedef unsigned short u16;
typedef __attribute__((ext_vector_type(8))) short short8;     // 8 bf16 (4 VGPRs) — MFMA A/B frag
typedef __attribute__((ext_vector_type(8))) unsigned short u16x8;
typedef __attribute__((ext_vector_type(4))) float floatx4;    // MFMA C/D frag

__device__ __forceinline__ u16 f2bf(float f) {
  unsigned u = __float_as_uint(f);
  u += 0x7FFFu + ((u >> 16) & 1u);   // RNE to bf16
  return (u16)(u >> 16);
}

// async global->LDS, 16B per lane; global addr is PER-LANE, LDS dest = wave-uniform base + lane*16
__device__ __forceinline__ void gld_lds16(const void* g, void* l) {
  __builtin_amdgcn_global_load_lds(
      (const __attribute__((address_space(1))) unsigned int*)g,
      (__attribute__((address_space(3))) unsigned int*)l, 16, 0, 0);
}

// fast tanh: 1 - 2/(e^{2x}+1). Exact +-1 asymptotes, ~6 VALU ops, |err| ~ 1e-7.
__device__ __forceinline__ float tanh_fast(float x) {
  float t = __expf(2.0f * x);
  return 1.0f - 2.0f / (t + 1.0f);
}

// W_attn (H,3H) fp32 -> W_e bf16 (H,2H)
__global__ void conv_we_k(const float* __restrict__ W, u16* __restrict__ dst) {
  const int h = blockIdx.x;
  const int t = threadIdx.x * 8;
  const float* sp = W + (size_t)h * 3072 + H + t;
  u16* dp = dst + (size_t)h * K2 + t;
  floatx4 x = *(const floatx4*)sp;
  floatx4 y = *(const floatx4*)(sp + 4);
  u16x8 o;
  o[0] = f2bf(x[0]); o[1] = f2bf(x[1]); o[2] = f2bf(x[2]); o[3] = f2bf(x[3]);
  o[4] = f2bf(y[0]); o[5] = f2bf(y[1]); o[6] = f2bf(y[2]); o[7] = f2bf(y[3]);
  *(u16x8*)dp = o;
}

// enc (S,B,2H) fp32 -> encb (B,S,2H) bf16. Pure BW pass (~384MB traffic).
__global__ void conv_enc_k(const float* __restrict__ enc, u16* __restrict__ dst) {
  const int sb = blockIdx.x;          // s*B + b
  const int s = sb >> 5;
  const int b = sb & 31;
  const int t = threadIdx.x * 8;
  const float* sp = enc + (size_t)sb * K2 + t;
  u16* dp = dst + ((size_t)b * S + s) * K2 + t;
  floatx4 x = *(const floatx4*)sp;
  floatx4 y = *(const floatx4*)(sp + 4);
  u16x8 o;
  o[0] = f2bf(x[0]); o[1] = f2bf(x[1]); o[2] = f2bf(x[2]); o[3] = f2bf(x[3]);
  o[4] = f2bf(y[0]); o[5] = f2bf(y[1]); o[6] = f2bf(y[2]); o[7] = f2bf(y[3]);
  *(u16x8*)dp = o;
}

// h_proj[b,h] = hidden[b,:] . W_attn[h, 0:H] + b_attn[h]   (fp32 exact path)
__global__ void hproj_k(const float* __restrict__ hidden, const float* __restrict__ W,
                        const float* __restrict__ b_attn, float* __restrict__ hp) {
  const int lane = threadIdx.x & 63;
  const int h = (blockIdx.x * blockDim.x + threadIdx.x) >> 6;
  float wr[16];
#pragma unroll
  for (int i = 0; i < 16; i++) wr[i] = W[(size_t)h * 3072 + lane + i * 64];
  for (int b = 0; b < B; b++) {
    float d = 0.f;
#pragma unroll
    for (int i = 0; i < 16; i++) d = fmaf(wr[i], hidden[b * H + lane + i * 64], d);
#pragma unroll
    for (int off = 32; off; off >>= 1) d += __shfl_xor(d, off);
    if (lane == 0) hp[b * H + h] = d + b_attn[h];
  }
}

// ===================== 256x256 8-phase GEMM (T2+T3+T4+T5) =====================
// 8 waves (2M x 4N), per-wave output 128x64, BK=64, 32 K-tiles, 2 tiles/iter.
// LDS 128KB: sA/sB x 2 bufs x 2 regions x (128 rows x 64 bf16).
// Round-6 change: ZIG-ZAG quadrant order with register-persistent frags.
// Per-buffer phase order (mh,nh): (0,0)->(0,1)->(1,1)->(1,0). A-frags reused
// across adjacent pairs; B[nh0] persists P1->P4 in regs. LDS reads per iter
// drop 96 -> 48 b128/wave (12/4/8/0 per phase) — balances LDS pipe (~576cy)
// against MFMA (~520cy) per phase instead of 2.2x LDS-bound.
// Stage rotation (region's last LDS read -> earliest legal stage phase):
//   sA[0][0]:P1->P2  sB[0][0]:P1->P3  sB[0][1]:P2->P4  sA[0][1]:P3->P5
//   sA[1][0]:P5->P6  sB[1][0]:P5->P7  sB[1][1]:P6->P8  sA[1][1]:P7->next P1
// vmcnt ledger (2 loads/unit/thread): drains vmcnt(6) at P4-end & P8-end keep
// the 3 newest units in flight; each drain covers every region read before
// the next drain. Last iter: P4 drains to 0 (P2..P8 stages skipped).
#define BM 256
#define BN 256
#define BK 64
#define NKT 32   // K2/BK

#define STG_A(BUF, MH, KT)                                                    \
  { _Pragma("unroll") for (int c_ = 0; c_ < 2; ++c_) {                        \
      const int ri_ = c_ * 64 + srow;                                         \
      const int rg_ = ((ri_ >> 6) << 7) + (MH) * 64 + (ri_ & 63);             \
      const int lg_ = sseg ^ (ri_ & 7);                                       \
      gld_lds16(Ab + (size_t)(s0 + rg_) * K2 + (KT) * BK + (lg_ << 3),        \
                (char*)&sA[BUF][MH][0] + c_ * 8192 + wv * 1024); } }

#define STG_B(BUF, NH, KT)                                                    \
  { _Pragma("unroll") for (int c_ = 0; c_ < 2; ++c_) {                        \
      const int ri_ = c_ * 64 + srow;                                         \
      const int rg_ = ((ri_ >> 5) << 6) + (NH) * 32 + (ri_ & 31);             \
      const int lg_ = sseg ^ (ri_ & 7);                                       \
      gld_lds16(Bw + (size_t)(h0 + rg_) * K2 + (KT) * BK + (lg_ << 3),        \
                (char*)&sB[BUF][NH][0] + c_ * 8192 + wv * 1024); } }

#define RD_A(BUF, MH)                                                         \
    _Pragma("unroll") for (int m_ = 0; m_ < 4; ++m_)                          \
      _Pragma("unroll") for (int k_ = 0; k_ < 2; ++k_)                        \
        af[m_][k_] = *(const short8*)(&sA[BUF][MH][0] + aoff[m_][k_]);

#define RD_B(DST, BUF, NH)                                                    \
    _Pragma("unroll") for (int n_ = 0; n_ < 2; ++n_)                          \
      _Pragma("unroll") for (int k_ = 0; k_ < 2; ++k_)                        \
        DST[n_][k_] = *(const short8*)(&sB[BUF][NH][0] + boff[n_][k_]);

#define MM(MH, NH, BFR)                                                       \
    _Pragma("unroll") for (int k_ = 0; k_ < 2; ++k_)                          \
      _Pragma("unroll") for (int m_ = 0; m_ < 4; ++m_)                        \
        _Pragma("unroll") for (int n_ = 0; n_ < 2; ++n_)                      \
          acc[(MH) * 4 + m_][(NH) * 2 + n_] =                                 \
              __builtin_amdgcn_mfma_f32_16x16x32_bf16(                        \
                  af[m_][k_], BFR[n_][k_],                                    \
                  acc[(MH) * 4 + m_][(NH) * 2 + n_], 0, 0, 0);

#define PH(READS, STAGE, MFMA_, DRAIN)                                        \
  {                                                                           \
    READS                                                                     \
    STAGE                                                                     \
    __builtin_amdgcn_s_barrier();                                             \
    asm volatile("s_waitcnt lgkmcnt(0)" ::: "memory");                        \
    __builtin_amdgcn_sched_barrier(0);                                        \
    __builtin_amdgcn_s_setprio(1);                                            \
    MFMA_                                                                     \
    __builtin_amdgcn_s_setprio(0);                                            \
    DRAIN                                                                     \
    __builtin_amdgcn_s_barrier();                                             \
  }

__global__ __launch_bounds__(512, 2) void gemm_8ph_k(
    const u16* __restrict__ A,      // (B,S,2H) bf16
    const u16* __restrict__ Bw,     // (H,2H) bf16
    const float* __restrict__ hp, const float* __restrict__ vw,
    float* __restrict__ attn) {
  __shared__ __align__(16) u16 sA[2][2][128 * 64];   // [buf][mh][row*64+k] 64KB
  __shared__ __align__(16) u16 sB[2][2][128 * 64];   // [buf][nh][row*64+k] 64KB

  const int tid = threadIdx.x;
  const int lane = tid & 63;
  const int wv = tid >> 6;       // 0..7
  const int wr = wv >> 2;        // 0..1 (M wave-row)
  const int wc = wv & 3;         // 0..3 (N wave-col)
  const int fr = lane & 15;
  const int kgrp = lane >> 4;    // 0..3
  const int srow = wv * 8 + (lane >> 3);  // staging rowidx within 64-row call
  const int sseg = lane & 7;              // staging physical seg

  const int bid = blockIdx.x;             // 512 blocks: ntile*128 + b*4 + mtile
  const int ntile = bid >> 7;             // 0..3
  const int b = (bid >> 2) & 31;
  const int mtile = bid & 3;              // fastest-varying (R1 lesson)
  const int s0 = mtile * BM;
  const int h0 = ntile * BN;

  const u16* Ab = A + (size_t)b * S * K2;

  // thread-invariant frag offsets (u16 units) within a 16KB region
  int aoff[4][2], boff[2][2];
#pragma unroll
  for (int m = 0; m < 4; ++m)
#pragma unroll
    for (int k = 0; k < 2; ++k)
      aoff[m][k] = (wr * 64 + m * 16 + fr) * 64 + ((((k << 2) + kgrp) ^ (fr & 7)) << 3);
#pragma unroll
  for (int n = 0; n < 2; ++n)
#pragma unroll
    for (int k = 0; k < 2; ++k)
      boff[n][k] = (wc * 32 + n * 16 + fr) * 64 + ((((k << 2) + kgrp) ^ (fr & 7)) << 3);

  floatx4 acc[8][4];
#pragma unroll
  for (int i = 0; i < 8; ++i)
#pragma unroll
    for (int j = 0; j < 4; ++j) acc[i][j] = (floatx4){0.f, 0.f, 0.f, 0.f};

  short8 af[4][2], bf0[2][2], bf1[2][2];  // persistent frag registers

  // ---- prologue: t0 all 4 regions + t1 {A10,B10,B11}; drain to 3 in flight
  STG_A(0, 0, 0) STG_B(0, 0, 0) STG_B(0, 1, 0) STG_A(0, 1, 0)
  STG_A(1, 0, 1) STG_B(1, 0, 1) STG_B(1, 1, 1)
  asm volatile("s_waitcnt vmcnt(6)" ::: "memory");   // t0 landed; t1 trio in flight
  __builtin_amdgcn_s_barrier();

  // ---- main loop: iter computes tiles 2it (buf0, P1-4) and 2it+1 (buf1, P5-8)
  for (int it = 0; it < 16; ++it) {
    const int t1 = 2 * it + 1, t2 = 2 * it + 2, t3 = 2 * it + 3;
    const bool Lst = (it == 15);
    // P1 (0,0): reads af<-A[0][0], bf0<-B[0][0]; stage A[1][1]<-t1
    PH(RD_A(0, 0) RD_B(bf0, 0, 0), STG_A(1, 1, t1), MM(0, 0, bf0), )
    // P2 (0,1): read bf1<-B[0][1]; stage A[0][0]<-t2
    PH(RD_B(bf1, 0, 1), if (!Lst) { STG_A(0, 0, t2) }, MM(0, 1, bf1), )
    // P3 (1,1): read af<-A[0][1]; stage B[0][0]<-t2
    PH(RD_A(0, 1), if (!Lst) { STG_B(0, 0, t2) }, MM(1, 1, bf1), )
    // P4 (1,0): no reads (af, bf0 persisted); stage B[0][1]<-t2; K-tile drain
    PH(, if (!Lst) { STG_B(0, 1, t2) }, MM(1, 0, bf0),
       if (Lst) { asm volatile("s_waitcnt vmcnt(0)" ::: "memory"); }
       else     { asm volatile("s_waitcnt vmcnt(6)" ::: "memory"); } )
    // P5 (0,0): reads af<-A[1][0], bf0<-B[1][0]; stage A[0][1]<-t2
    PH(RD_A(1, 0) RD_B(bf0, 1, 0), if (!Lst) { STG_A(0, 1, t2) }, MM(0, 0, bf0), )
    // P6 (0,1): read bf1<-B[1][1]; stage A[1][0]<-t3
    PH(RD_B(bf1, 1, 1), if (!Lst) { STG_A(1, 0, t3) }, MM(0, 1, bf1), )
    // P7 (1,1): read af<-A[1][1]; stage B[1][0]<-t3
    PH(RD_A(1, 1), if (!Lst) { STG_B(1, 0, t3) }, MM(1, 1, bf1), )
    // P8 (1,0): no reads; stage B[1][1]<-t3; K-tile drain
    PH(, if (!Lst) { STG_B(1, 1, t3) }, MM(1, 0, bf0),
       if (!Lst) { asm volatile("s_waitcnt vmcnt(6)" ::: "memory"); } )
  }

  // ---- epilogue: tanh + v-weighted h-reduction. C/D: col=lane&15, row=(lane>>4)*4+reg
  const int col = fr;
  const int rgrp = lane >> 4;
  float hv[4], vv[4];
#pragma unroll
  for (int nf = 0; nf < 4; ++nf) {
    const int h = h0 + wc * 64 + nf * 16 + col;
    hv[nf] = hp[b * H + h];
    vv[nf] = vw[h];
  }
#pragma unroll
  for (int mf = 0; mf < 8; ++mf) {
#pragma unroll
    for (int r = 0; r < 4; ++r) {
      float part = 0.f;
#pragma unroll
      for (int nf = 0; nf < 4; ++nf) part += tanh_fast(acc[mf][nf][r] + hv[nf]) * vv[nf];
      part += __shfl_xor(part, 1);
      part += __shfl_xor(part, 2);
      part += __shfl_xor(part, 4);
      part += __shfl_xor(part, 8);   // sum over 16 col-lanes; preserves rgrp
      if (col == 0)
        atomicAdd(&attn[b * S + s0 + wr * 128 + mf * 16 + rgrp * 4 + r], part);
    }
  }
}

__global__ void softmax_k(const float* __restrict__ attn, float* __restrict__ out) {
  __shared__ float red[8];
  const int b = blockIdx.x;
  const int tid = threadIdx.x;
  const float* row = attn + b * S;
  float v[4];
#pragma unroll
  for (int i = 0; i < 4; i++) v[i] = row[tid + i * 256];
  float m = fmaxf(fmaxf(v[0], v[1]), fmaxf(v[2], v[3]));
#pragma unroll
  for (int off = 32; off; off >>= 1) m = fmaxf(m, __shfl_xor(m, off));
  if ((tid & 63) == 0) red[tid >> 6] = m;
  __syncthreads();
  m = fmaxf(fmaxf(red[0], red[1]), fmaxf(red[2], red[3]));
  float e[4], sum = 0.f;
#pragma unroll
  for (int i = 0; i < 4; i++) { e[i] = __expf(v[i] - m); sum += e[i]; }
#pragma unroll
  for (int off = 32; off; off >>= 1) sum += __shfl_xor(sum, off);
  __syncthreads();
  if ((tid & 63) == 0) red[4 + (tid >> 6)] = sum;
  __syncthreads();
  sum = red[4] + red[5] + red[6] + red[7];
  const float inv = 1.0f / sum;
#pragma unroll
  for (int i = 0; i < 4; i++) out[b * S + tid + i * 256] = e[i] * inv;
}

extern "C" void kernel_launch(void* const* d_in, const int* in_sizes, int n_in,
                              void* d_out, int out_size, void* d_ws, size_t ws_size,
                              hipStream_t stream) {
  const float* enc    = (const float*)d_in[0];  // (S,B,2H)
  const float* hidden = (const float*)d_in[1];  // (B,H)
  // d_in[2] = cell — unused by the reference
  const float* W_attn = (const float*)d_in[3];  // (H,3H)
  const float* b_attn = (const float*)d_in[4];  // (H)
  const float* v_w    = (const float*)d_in[5];  // (H)
  float* out = (float*)d_out;                   // (B,S)

  char* ws = (char*)d_ws;
  float* attn = (float*)ws;                                  // 128 KiB
  float* hp   = (float*)(ws + 131072);                       // 128 KiB
  u16* Web    = (u16*)(ws + 262144);                         // 4 MiB
  u16* encb   = (u16*)(ws + 4456448);                        // 128 MiB (B,S,2H) bf16

  hipMemsetAsync(attn, 0, B * S * sizeof(float), stream);    // ws is 0xAA-poisoned each call
  conv_we_k<<<H, 256, 0, stream>>>(W_attn, Web);
  hproj_k<<<256, 256, 0, stream>>>(hidden, W_attn, b_attn, hp);
  conv_enc_k<<<S * B, 256, 0, stream>>>(enc, encb);
  gemm_8ph_k<<<512, 512, 0, stream>>>(encb, Web, hp, v_w, attn);
  softmax_k<<<B, 256, 0, stream>>>(attn, out);
}